// Round 6
// baseline (2238.143 us; speedup 1.0000x reference)
//
#include <hip/hip_runtime.h>
#include <math.h>

#define NB 4
#define NC 128
#define NT 16
#define NH 56
#define NW 56
#define NHW 3136
#define NF 9
#define NO 144
#define NI 2192
#define NEPS 1e-5f

__constant__ float COS16[16] = {
  1.0f, 0.9238795325f, 0.7071067812f, 0.3826834324f,
  0.0f, -0.3826834324f, -0.7071067812f, -0.9238795325f,
  -1.0f, -0.9238795325f, -0.7071067812f, -0.3826834324f,
  0.0f, 0.3826834324f, 0.7071067812f, 0.9238795325f};
__constant__ float SIN16[16] = {
  0.0f, 0.3826834324f, 0.7071067812f, 0.9238795325f,
  1.0f, 0.9238795325f, 0.7071067812f, 0.3826834324f,
  0.0f, -0.3826834324f, -0.7071067812f, -0.9238795325f,
  -1.0f, -0.9238795325f, -0.7071067812f, -0.3826834324f};

// K1: w_o (correlation), softmax -> w_s, a, x2 = x + a_shift
__global__ __launch_bounds__(256) void k_cor(
    const float* __restrict__ x, const float* __restrict__ wcor,
    float* __restrict__ wo, float* __restrict__ x2) {
  int px = blockIdx.x * 256 + threadIdx.x;
  if (px >= NHW) return;
  int t = blockIdx.y;
  int b = blockIdx.z;
  int h = px / NW, w = px % NW;
  int tn = (t < NT - 1) ? t + 1 : NT - 1;

  int  no_[9];
  bool nv_[9];
  #pragma unroll
  for (int ki = 0; ki < 3; ki++) {
    #pragma unroll
    for (int kj = 0; kj < 3; kj++) {
      int hh = h + ki - 1, ww = w + kj - 1;
      nv_[ki*3+kj] = (hh >= 0 && hh < NH && ww >= 0 && ww < NW);
      no_[ki*3+kj] = hh * NW + ww;
    }
  }

  float acc[9];
  #pragma unroll
  for (int i = 0; i < 9; i++) acc[i] = 0.0f;

  for (int c = 0; c < NC; c++) {
    const float* xt  = x + (size_t)((b*NC + c)*NT + t ) * NHW;
    const float* xtn = x + (size_t)((b*NC + c)*NT + tn) * NHW;
    float xv = xt[px];
    const float* wc = wcor + (c*NT + t) * 9;
    #pragma unroll
    for (int i = 0; i < 9; i++) {
      float xn = nv_[i] ? xtn[no_[i]] : 0.0f;
      acc[i] = fmaf(xv * wc[i], xn, acc[i]);
    }
  }

  // store w_o
  #pragma unroll
  for (int i = 0; i < 9; i++)
    wo[(size_t)((b*9 + i)*NT + t) * NHW + px] = acc[i];

  // softmax over the 9 positions
  float m = acc[0];
  #pragma unroll
  for (int i = 1; i < 9; i++) m = fmaxf(m, acc[i]);
  float s = 0.0f;
  #pragma unroll
  for (int i = 0; i < 9; i++) { acc[i] = __expf(acc[i] - m); s += acc[i]; }
  float inv = 1.0f / s;
  #pragma unroll
  for (int i = 0; i < 9; i++) acc[i] *= inv;

  if (t == 0) return;  // a[:, :, 0] is dropped by a_shift

  for (int c = 0; c < NC; c++) {
    const float* xt = x + (size_t)((b*NC + c)*NT + t) * NHW;
    float a = 0.0f;
    #pragma unroll
    for (int i = 0; i < 9; i++) {
      float xn = nv_[i] ? xt[no_[i]] : 0.0f;
      a = fmaf(acc[i], xn, a);
    }
    int o = ((b*NC + c)*NT + (t - 1)) * NHW + px;
    x2[o] = x[o] + a;
    if (t == NT - 1) {           // x2[15] = x[15] (a_shift zero-padded)
      int o2 = o + NHW;
      x2[o2] = x[o2];
    }
  }
}

// K2: rfft along T (16 -> 9 complex), norm='ortho'
__global__ __launch_bounds__(256) void k_fft(
    const float* __restrict__ x2, float* __restrict__ xtr, float* __restrict__ xti) {
  int px = blockIdx.x * 256 + threadIdx.x;
  if (px >= NHW) return;
  int c = blockIdx.y, b = blockIdx.z;
  const float* src = x2 + (size_t)((b*NC + c)*NT) * NHW + px;
  float v[NT];
  #pragma unroll
  for (int tt = 0; tt < NT; tt++) v[tt] = src[tt * NHW];
  float* dr = xtr + (size_t)((b*NC + c)*NF) * NHW + px;
  float* di = xti + (size_t)((b*NC + c)*NF) * NHW + px;
  #pragma unroll
  for (int k = 0; k < NF; k++) {
    float sr = 0.0f, si = 0.0f;
    #pragma unroll
    for (int tt = 0; tt < NT; tt++) {
      int j = (k * tt) & 15;
      sr = fmaf(v[tt], COS16[j], sr);
      si = fmaf(-v[tt], SIN16[j], si);
    }
    dr[k * NHW] = 0.25f * sr;
    di[k * NHW] = 0.25f * si;
  }
}

// K3: iterm = Wg @ x_c   (x_c = [x2 flattened (2048); w_o flattened (144)])
__global__ __launch_bounds__(256) void k_iterm(
    const float* __restrict__ x2, const float* __restrict__ wo,
    const float* __restrict__ Wg, float* __restrict__ itm) {
  int px = blockIdx.x * 256 + threadIdx.x;
  if (px >= NHW) return;
  int o0 = blockIdx.y * 16;    // 9 chunks of 16 -> 144
  int b  = blockIdx.z;
  const float* xb = x2 + (size_t)b * NC * NT * NHW + px;
  const float* wb = wo + (size_t)b * 9  * NT * NHW + px;
  float acc[16];
  #pragma unroll
  for (int r = 0; r < 16; r++) acc[r] = 0.0f;
  for (int i = 0; i < NC*NT; i++) {
    float v = xb[(size_t)i * NHW];
    #pragma unroll
    for (int r = 0; r < 16; r++)
      acc[r] = fmaf(Wg[(o0 + r) * NI + i], v, acc[r]);
  }
  for (int i = 0; i < 9*NT; i++) {
    float v = wb[(size_t)i * NHW];
    #pragma unroll
    for (int r = 0; r < 16; r++)
      acc[r] = fmaf(Wg[(o0 + r) * NI + NC*NT + i], v, acc[r]);
  }
  #pragma unroll
  for (int r = 0; r < 16; r++)
    itm[(size_t)(b*NO + o0 + r) * NHW + px] = acc[r];
}

// K4: y_in = x_t * ffc * w1 ; y = Wl @ y_in (complex, channel mix)
__global__ __launch_bounds__(256) void k_ywl(
    const float* __restrict__ xtr, const float* __restrict__ xti,
    const float* __restrict__ itm, const float* __restrict__ w1r,
    const float* __restrict__ w1i, const float* __restrict__ Wlr,
    const float* __restrict__ Wli, float* __restrict__ yr, float* __restrict__ yi) {
  int px = blockIdx.x * 256 + threadIdx.x;
  if (px >= NHW) return;
  int o0 = blockIdx.y * 16;         // 8 chunks of 16 -> 128
  int bt = blockIdx.z;              // b*9 + tt
  int b = bt / NF, tt = bt % NF;
  float ar[16], ai[16];
  #pragma unroll
  for (int r = 0; r < 16; r++) { ar[r] = 0.0f; ai[r] = 0.0f; }
  const float* xrb = xtr + (size_t)(b*NC*NF + tt) * NHW + px;
  const float* xib = xti + (size_t)(b*NC*NF + tt) * NHW + px;
  const float* ib  = itm + (size_t)b * NO * NHW + px;
  for (int c = 0; c < NC; c++) {
    float xr = xrb[(size_t)c * NF * NHW];
    float xi = xib[(size_t)c * NF * NHW];
    int f0 = c*18 + tt*2;           // repeat-G reshape: o = flat>>4
    float fr = ib[(size_t)(f0 >> 4) * NHW];
    float fi = ib[(size_t)((f0 + 1) >> 4) * NHW];
    float wr1 = w1r[c*NF + tt], wi1 = w1i[c*NF + tt];
    float t1r = xr*fr - xi*fi;
    float t1i = xr*fi + xi*fr;
    float vr = t1r*wr1 - t1i*wi1;
    float vi = t1r*wi1 + t1i*wr1;
    #pragma unroll
    for (int r = 0; r < 16; r++) {
      float wr = Wlr[(o0 + r)*NC + c], wi = Wli[(o0 + r)*NC + c];
      ar[r] = fmaf(wr, vr, fmaf(-wi, vi, ar[r]));
      ai[r] = fmaf(wr, vi, fmaf( wi, vr, ai[r]));
    }
  }
  #pragma unroll
  for (int r = 0; r < 16; r++) {
    size_t o = (size_t)((b*NC + o0 + r)*NF + tt) * NHW + px;
    yr[o] = ar[r];
    yi[o] = ai[r];
  }
}

// K5: BN statistics (per-channel sum / sumsq over B, freq, H, W)
__global__ __launch_bounds__(256) void k_bnstats(
    const float* __restrict__ yr, const float* __restrict__ yi,
    float* __restrict__ stats) {
  int c = blockIdx.x, b = blockIdx.y;
  const float* pr = yr + (size_t)(b*NC + c) * NF * NHW;
  const float* pi = yi + (size_t)(b*NC + c) * NF * NHW;
  const int n = NF * NHW;
  float sr = 0, qr = 0, si = 0, qi = 0;
  for (int i = threadIdx.x; i < n; i += 256) {
    float vr = pr[i], vi = pi[i];
    sr += vr; qr += vr*vr; si += vi; qi += vi*vi;
  }
  #pragma unroll
  for (int off = 32; off > 0; off >>= 1) {
    sr += __shfl_down(sr, off);
    qr += __shfl_down(qr, off);
    si += __shfl_down(si, off);
    qi += __shfl_down(qi, off);
  }
  __shared__ float red[4][4];
  int lane = threadIdx.x & 63, wid = threadIdx.x >> 6;
  if (lane == 0) { red[wid][0]=sr; red[wid][1]=qr; red[wid][2]=si; red[wid][3]=qi; }
  __syncthreads();
  if (threadIdx.x == 0) {
    float a=0, q=0, cs=0, d=0;
    #pragma unroll
    for (int wv = 0; wv < 4; wv++) { a+=red[wv][0]; q+=red[wv][1]; cs+=red[wv][2]; d+=red[wv][3]; }
    atomicAdd(&stats[c],        a);
    atomicAdd(&stats[NC + c],   q);
    atomicAdd(&stats[2*NC + c], cs);
    atomicAdd(&stats[3*NC + c], d);
  }
}

// K6: BN apply, *alpha1, irfft (9 complex -> 16 real, ortho), + identity + bias_p
__global__ __launch_bounds__(256) void k_final(
    const float* __restrict__ yr, const float* __restrict__ yi,
    const float* __restrict__ stats,
    const float* __restrict__ gr, const float* __restrict__ br,
    const float* __restrict__ gi, const float* __restrict__ bi,
    const float* __restrict__ alpha, const float* __restrict__ biasp,
    const float* __restrict__ x, float* __restrict__ out) {
  int px = blockIdx.x * 256 + threadIdx.x;
  if (px >= NHW) return;
  int c = blockIdx.y, b = blockIdx.z;
  const float ninv = 1.0f / (float)(NB * NF * NHW);
  float mr = stats[c] * ninv;
  float vr = stats[NC + c] * ninv - mr*mr;
  float mi = stats[2*NC + c] * ninv;
  float vi = stats[3*NC + c] * ninv - mi*mi;
  float sclr = rsqrtf(vr + NEPS) * gr[c];
  float scli = rsqrtf(vi + NEPS) * gi[c];
  float al = alpha[c];
  float scr = sclr * al, sci = scli * al;
  float shr = (br[c] - mr * sclr) * al;
  float shi = (bi[c] - mi * scli) * al;

  const float* prr = yr + (size_t)((b*NC + c)*NF) * NHW + px;
  const float* pii = yi + (size_t)((b*NC + c)*NF) * NHW + px;
  float Yr[NF], Yi[NF];
  #pragma unroll
  for (int k = 0; k < NF; k++) {
    Yr[k] = prr[k * NHW] * scr + shr;
    Yi[k] = pii[k * NHW] * sci + shi;
  }
  const float* xb = x  + (size_t)((b*NC + c)*NT) * NHW + px;
  float*       ob = out + (size_t)((b*NC + c)*NT) * NHW + px;
  float bp = biasp[c];
  #pragma unroll
  for (int n = 0; n < NT; n++) {
    float s = Yr[0] + ((n & 1) ? -Yr[8] : Yr[8]);
    #pragma unroll
    for (int k = 1; k < 8; k++) {
      int j = (k * n) & 15;
      s = fmaf(2.0f * Yr[k], COS16[j], s);
      s = fmaf(-2.0f * Yi[k], SIN16[j], s);
    }
    ob[n * NHW] = xb[n * NHW] + 0.25f * s + bp;
  }
}

extern "C" void kernel_launch(void* const* d_in, const int* in_sizes, int n_in,
                              void* d_out, int out_size, void* d_ws, size_t ws_size,
                              hipStream_t stream) {
  const float* x     = (const float*)d_in[0];
  const float* wcor  = (const float*)d_in[1];
  const float* Wg    = (const float*)d_in[2];
  const float* w1r   = (const float*)d_in[3];
  const float* w1i   = (const float*)d_in[4];
  const float* Wlr   = (const float*)d_in[5];
  const float* Wli   = (const float*)d_in[6];
  const float* gr    = (const float*)d_in[7];
  const float* br    = (const float*)d_in[8];
  const float* gi    = (const float*)d_in[9];
  const float* bi    = (const float*)d_in[10];
  const float* alpha = (const float*)d_in[11];
  const float* biasp = (const float*)d_in[12];
  float* out = (float*)d_out;

  float* ws  = (float*)d_ws;
  float* wo  = ws;                                  // 4*9*16*3136   = 1,806,336
  float* x2  = wo  + (size_t)NB*9*NT*NHW;           // 4*128*16*3136 = 25,690,112
  float* xtr = x2  + (size_t)NB*NC*NT*NHW;          // 4*128*9*3136  = 14,450,688
  float* xti = xtr + (size_t)NB*NC*NF*NHW;
  float* itm = xti + (size_t)NB*NC*NF*NHW;          // 4*144*3136    = 1,806,336
  float* yr  = itm + (size_t)NB*NO*NHW;
  float* yi  = yr  + (size_t)NB*NC*NF*NHW;
  float* stats = yi + (size_t)NB*NC*NF*NHW;         // 512 floats

  hipMemsetAsync(stats, 0, 4*NC*sizeof(float), stream);

  dim3 blk(256);
  int pxb = (NHW + 255) / 256;  // 13

  k_cor    <<<dim3(pxb, NT, NB),    blk, 0, stream>>>(x, wcor, wo, x2);
  k_fft    <<<dim3(pxb, NC, NB),    blk, 0, stream>>>(x2, xtr, xti);
  k_iterm  <<<dim3(pxb, 9, NB),     blk, 0, stream>>>(x2, wo, Wg, itm);
  k_ywl    <<<dim3(pxb, 8, NB*NF),  blk, 0, stream>>>(xtr, xti, itm, w1r, w1i, Wlr, Wli, yr, yi);
  k_bnstats<<<dim3(NC, NB),         blk, 0, stream>>>(yr, yi, stats);
  k_final  <<<dim3(pxb, NC, NB),    blk, 0, stream>>>(yr, yi, stats, gr, br, gi, bi, alpha, biasp, x, out);
}

// Round 8
// 1044.196 us; speedup vs baseline: 2.1434x; 2.1434x over previous
//
#include <hip/hip_runtime.h>
#include <math.h>

#define NB 4
#define NC 128
#define NT 16
#define NH 56
#define NW 56
#define NHW 3136
#define NF 9
#define NO 144
#define NI 2192
#define KP 2208          // NI padded to multiple of 32
#define KSTEPS 69        // KP / 32
#define NEPS 1e-5f

typedef __attribute__((ext_vector_type(8))) short short8;
typedef __attribute__((ext_vector_type(4))) float f32x4;

__constant__ float COS16[16] = {
  1.0f, 0.9238795325f, 0.7071067812f, 0.3826834324f,
  0.0f, -0.3826834324f, -0.7071067812f, -0.9238795325f,
  -1.0f, -0.9238795325f, -0.7071067812f, -0.3826834324f,
  0.0f, 0.3826834324f, 0.7071067812f, 0.9238795325f};
__constant__ float SIN16[16] = {
  0.0f, 0.3826834324f, 0.7071067812f, 0.9238795325f,
  1.0f, 0.9238795325f, 0.7071067812f, 0.3826834324f,
  0.0f, -0.3826834324f, -0.7071067812f, -0.9238795325f,
  -1.0f, -0.9238795325f, -0.7071067812f, -0.3826834324f};

__device__ inline unsigned short f2bf(float f) {
  union { float f; unsigned u; } v; v.f = f;
  unsigned r = v.u + 0x7fff + ((v.u >> 16) & 1);   // RNE
  return (unsigned short)(r >> 16);
}

// K1: w_o (correlation), softmax -> w_s, a, x2 = x + a_shift
__global__ __launch_bounds__(256) void k_cor(
    const float* __restrict__ x, const float* __restrict__ wcor,
    float* __restrict__ wo, float* __restrict__ x2) {
  int px = blockIdx.x * 256 + threadIdx.x;
  if (px >= NHW) return;
  int t = blockIdx.y;
  int b = blockIdx.z;
  int h = px / NW, w = px % NW;
  int tn = (t < NT - 1) ? t + 1 : NT - 1;

  int  no_[9];
  bool nv_[9];
  #pragma unroll
  for (int ki = 0; ki < 3; ki++) {
    #pragma unroll
    for (int kj = 0; kj < 3; kj++) {
      int hh = h + ki - 1, ww = w + kj - 1;
      nv_[ki*3+kj] = (hh >= 0 && hh < NH && ww >= 0 && ww < NW);
      no_[ki*3+kj] = hh * NW + ww;
    }
  }

  float acc[9];
  #pragma unroll
  for (int i = 0; i < 9; i++) acc[i] = 0.0f;

  for (int c = 0; c < NC; c++) {
    const float* xt  = x + (size_t)((b*NC + c)*NT + t ) * NHW;
    const float* xtn = x + (size_t)((b*NC + c)*NT + tn) * NHW;
    float xv = xt[px];
    const float* wc = wcor + (c*NT + t) * 9;
    #pragma unroll
    for (int i = 0; i < 9; i++) {
      float xn = nv_[i] ? xtn[no_[i]] : 0.0f;
      acc[i] = fmaf(xv * wc[i], xn, acc[i]);
    }
  }

  #pragma unroll
  for (int i = 0; i < 9; i++)
    wo[(size_t)((b*9 + i)*NT + t) * NHW + px] = acc[i];

  float m = acc[0];
  #pragma unroll
  for (int i = 1; i < 9; i++) m = fmaxf(m, acc[i]);
  float s = 0.0f;
  #pragma unroll
  for (int i = 0; i < 9; i++) { acc[i] = __expf(acc[i] - m); s += acc[i]; }
  float inv = 1.0f / s;
  #pragma unroll
  for (int i = 0; i < 9; i++) acc[i] *= inv;

  if (t == 0) return;

  for (int c = 0; c < NC; c++) {
    const float* xt = x + (size_t)((b*NC + c)*NT + t) * NHW;
    float a = 0.0f;
    #pragma unroll
    for (int i = 0; i < 9; i++) {
      float xn = nv_[i] ? xt[no_[i]] : 0.0f;
      a = fmaf(acc[i], xn, a);
    }
    int o = ((b*NC + c)*NT + (t - 1)) * NHW + px;
    x2[o] = x[o] + a;
    if (t == NT - 1) {
      int o2 = o + NHW;
      x2[o2] = x[o2];
    }
  }
}

// Prep A: Wg fp32 [144][2192] -> bf16 [144][KP] (zero-padded K)
__global__ __launch_bounds__(256) void k_wgbf(
    const float* __restrict__ Wg, unsigned short* __restrict__ WgBf) {
  int o = blockIdx.x;
  for (int k = threadIdx.x; k < KP; k += 256)
    WgBf[(size_t)o * KP + k] = (k < NI) ? f2bf(Wg[(size_t)o * NI + k]) : 0;
}

// Prep B: transpose+convert x_c = [x2(2048); wo(144)] from [k][px] -> xcT[b][px][k] bf16
__global__ __launch_bounds__(256) void k_xct(
    const float* __restrict__ x2, const float* __restrict__ wo,
    unsigned short* __restrict__ xcT) {
  __shared__ float tile[32][33];
  int b = blockIdx.z;
  int k0 = blockIdx.y * 32;   // 69 tiles, last covers pad
  int p0 = blockIdx.x * 32;   // 98 tiles, 3136 = 98*32 exact
  int tx = threadIdx.x & 31, ty = threadIdx.x >> 5;  // tx 0..31, ty 0..7
  #pragma unroll
  for (int r = 0; r < 4; r++) {
    int k = k0 + ty * 4 + r;
    float v = 0.0f;
    if (k < NI) {
      const float* src = (k < NC*NT)
        ? x2 + ((size_t)b * NC * NT + k) * NHW
        : wo + ((size_t)b * NO + (k - NC*NT)) * NHW;
      v = src[p0 + tx];
    }
    tile[ty * 4 + r][tx] = v;
  }
  __syncthreads();
  #pragma unroll
  for (int r = 0; r < 4; r++) {
    int py = ty * 4 + r;
    xcT[((size_t)b * NHW + p0 + py) * KP + k0 + tx] = f2bf(tile[tx][py]);
  }
}

// K3 (MFMA): itm[b][o][px] = sum_k Wg[o][k] * Xc[b][k][px]
// D = A*B, M=px(16/wave), N=o(48/wave, 3 frags), K=KP.
// A = xcT rows (px-major, k-contig); B[k][n=o] = WgBf[o][k] (k-contig per lane).
__global__ __launch_bounds__(64) void k_iterm_mfma(
    const unsigned short* __restrict__ xcT, const unsigned short* __restrict__ WgBf,
    float* __restrict__ itm) {
  int lane = threadIdx.x;
  int lm  = lane & 15;
  int lk8 = lane >> 4;                 // 0..3
  int px0 = blockIdx.x * 16;           // 196 tiles/b
  int og  = blockIdx.y * 48;           // 3 groups
  int b   = blockIdx.z;

  const unsigned short* Arow = xcT + ((size_t)b * NHW + px0 + lm) * KP + lk8 * 8;
  const unsigned short* Brow0 = WgBf + (size_t)(og + 0*16 + lm) * KP + lk8 * 8;
  const unsigned short* Brow1 = WgBf + (size_t)(og + 1*16 + lm) * KP + lk8 * 8;
  const unsigned short* Brow2 = WgBf + (size_t)(og + 2*16 + lm) * KP + lk8 * 8;

  f32x4 acc0 = {0,0,0,0}, acc1 = {0,0,0,0}, acc2 = {0,0,0,0};

  #pragma unroll 2
  for (int ks = 0; ks < KSTEPS; ks++) {
    int k0 = ks * 32;
    short8 a  = *(const short8*)(Arow + k0);
    short8 b0 = *(const short8*)(Brow0 + k0);
    short8 b1 = *(const short8*)(Brow1 + k0);
    short8 b2 = *(const short8*)(Brow2 + k0);
    acc0 = __builtin_amdgcn_mfma_f32_16x16x32_bf16(a, b0, acc0, 0, 0, 0);
    acc1 = __builtin_amdgcn_mfma_f32_16x16x32_bf16(a, b1, acc1, 0, 0, 0);
    acc2 = __builtin_amdgcn_mfma_f32_16x16x32_bf16(a, b2, acc2, 0, 0, 0);
  }

  // D: row(px) = lk8*4 + reg, col(o) = lm  [measured m89 C/D mapping]
  #pragma unroll
  for (int reg = 0; reg < 4; reg++) {
    int px = px0 + lk8 * 4 + reg;
    itm[((size_t)b * NO + og + 0*16 + lm) * NHW + px] = acc0[reg];
    itm[((size_t)b * NO + og + 1*16 + lm) * NHW + px] = acc1[reg];
    itm[((size_t)b * NO + og + 2*16 + lm) * NHW + px] = acc2[reg];
  }
}

// K2: rfft along T (16 -> 9 complex), norm='ortho'
__global__ __launch_bounds__(256) void k_fft(
    const float* __restrict__ x2, float* __restrict__ xtr, float* __restrict__ xti) {
  int px = blockIdx.x * 256 + threadIdx.x;
  if (px >= NHW) return;
  int c = blockIdx.y, b = blockIdx.z;
  const float* src = x2 + (size_t)((b*NC + c)*NT) * NHW + px;
  float v[NT];
  #pragma unroll
  for (int tt = 0; tt < NT; tt++) v[tt] = src[tt * NHW];
  float* dr = xtr + (size_t)((b*NC + c)*NF) * NHW + px;
  float* di = xti + (size_t)((b*NC + c)*NF) * NHW + px;
  #pragma unroll
  for (int k = 0; k < NF; k++) {
    float sr = 0.0f, si = 0.0f;
    #pragma unroll
    for (int tt = 0; tt < NT; tt++) {
      int j = (k * tt) & 15;
      sr = fmaf(v[tt], COS16[j], sr);
      si = fmaf(-v[tt], SIN16[j], si);
    }
    dr[k * NHW] = 0.25f * sr;
    di[k * NHW] = 0.25f * si;
  }
}

// K4: y_in = x_t * ffc * w1 ; y = Wl @ y_in (complex, channel mix)
__global__ __launch_bounds__(256) void k_ywl(
    const float* __restrict__ xtr, const float* __restrict__ xti,
    const float* __restrict__ itm, const float* __restrict__ w1r,
    const float* __restrict__ w1i, const float* __restrict__ Wlr,
    const float* __restrict__ Wli, float* __restrict__ yr, float* __restrict__ yi) {
  int px = blockIdx.x * 256 + threadIdx.x;
  if (px >= NHW) return;
  int o0 = blockIdx.y * 16;
  int bt = blockIdx.z;
  int b = bt / NF, tt = bt % NF;
  float ar[16], ai[16];
  #pragma unroll
  for (int r = 0; r < 16; r++) { ar[r] = 0.0f; ai[r] = 0.0f; }
  const float* xrb = xtr + (size_t)(b*NC*NF + tt) * NHW + px;
  const float* xib = xti + (size_t)(b*NC*NF + tt) * NHW + px;
  const float* ib  = itm + (size_t)b * NO * NHW + px;
  for (int c = 0; c < NC; c++) {
    float xr = xrb[(size_t)c * NF * NHW];
    float xi = xib[(size_t)c * NF * NHW];
    int f0 = c*18 + tt*2;
    float fr = ib[(size_t)(f0 >> 4) * NHW];
    float fi = ib[(size_t)((f0 + 1) >> 4) * NHW];
    float wr1 = w1r[c*NF + tt], wi1 = w1i[c*NF + tt];
    float t1r = xr*fr - xi*fi;
    float t1i = xr*fi + xi*fr;
    float vr = t1r*wr1 - t1i*wi1;
    float vi = t1r*wi1 + t1i*wr1;
    #pragma unroll
    for (int r = 0; r < 16; r++) {
      float wr = Wlr[(o0 + r)*NC + c], wi = Wli[(o0 + r)*NC + c];
      ar[r] = fmaf(wr, vr, fmaf(-wi, vi, ar[r]));
      ai[r] = fmaf(wr, vi, fmaf( wi, vr, ai[r]));
    }
  }
  #pragma unroll
  for (int r = 0; r < 16; r++) {
    size_t o = (size_t)((b*NC + o0 + r)*NF + tt) * NHW + px;
    yr[o] = ar[r];
    yi[o] = ai[r];
  }
}

// K5: BN statistics (per-channel sum / sumsq over B, freq, H, W)
__global__ __launch_bounds__(256) void k_bnstats(
    const float* __restrict__ yr, const float* __restrict__ yi,
    float* __restrict__ stats) {
  int c = blockIdx.x, b = blockIdx.y;
  const float* pr = yr + (size_t)(b*NC + c) * NF * NHW;
  const float* pi = yi + (size_t)(b*NC + c) * NF * NHW;
  const int n = NF * NHW;
  float sr = 0, qr = 0, si = 0, qi = 0;
  for (int i = threadIdx.x; i < n; i += 256) {
    float vr = pr[i], vi = pi[i];
    sr += vr; qr += vr*vr; si += vi; qi += vi*vi;
  }
  #pragma unroll
  for (int off = 32; off > 0; off >>= 1) {
    sr += __shfl_down(sr, off);
    qr += __shfl_down(qr, off);
    si += __shfl_down(si, off);
    qi += __shfl_down(qi, off);
  }
  __shared__ float red[4][4];
  int lane = threadIdx.x & 63, wid = threadIdx.x >> 6;
  if (lane == 0) { red[wid][0]=sr; red[wid][1]=qr; red[wid][2]=si; red[wid][3]=qi; }
  __syncthreads();
  if (threadIdx.x == 0) {
    float a=0, q=0, cs=0, d=0;
    #pragma unroll
    for (int wv = 0; wv < 4; wv++) { a+=red[wv][0]; q+=red[wv][1]; cs+=red[wv][2]; d+=red[wv][3]; }
    atomicAdd(&stats[c],        a);
    atomicAdd(&stats[NC + c],   q);
    atomicAdd(&stats[2*NC + c], cs);
    atomicAdd(&stats[3*NC + c], d);
  }
}

// K6: BN apply, *alpha1, irfft (9 complex -> 16 real, ortho), + identity + bias_p
__global__ __launch_bounds__(256) void k_final(
    const float* __restrict__ yr, const float* __restrict__ yi,
    const float* __restrict__ stats,
    const float* __restrict__ gr, const float* __restrict__ br,
    const float* __restrict__ gi, const float* __restrict__ bi,
    const float* __restrict__ alpha, const float* __restrict__ biasp,
    const float* __restrict__ x, float* __restrict__ out) {
  int px = blockIdx.x * 256 + threadIdx.x;
  if (px >= NHW) return;
  int c = blockIdx.y, b = blockIdx.z;
  const float ninv = 1.0f / (float)(NB * NF * NHW);
  float mr = stats[c] * ninv;
  float vr = stats[NC + c] * ninv - mr*mr;
  float mi = stats[2*NC + c] * ninv;
  float vi = stats[3*NC + c] * ninv - mi*mi;
  float sclr = rsqrtf(vr + NEPS) * gr[c];
  float scli = rsqrtf(vi + NEPS) * gi[c];
  float al = alpha[c];
  float scr = sclr * al, sci = scli * al;
  float shr = (br[c] - mr * sclr) * al;
  float shi = (bi[c] - mi * scli) * al;

  const float* prr = yr + (size_t)((b*NC + c)*NF) * NHW + px;
  const float* pii = yi + (size_t)((b*NC + c)*NF) * NHW + px;
  float Yr[NF], Yi[NF];
  #pragma unroll
  for (int k = 0; k < NF; k++) {
    Yr[k] = prr[k * NHW] * scr + shr;
    Yi[k] = pii[k * NHW] * sci + shi;
  }
  const float* xb = x  + (size_t)((b*NC + c)*NT) * NHW + px;
  float*       ob = out + (size_t)((b*NC + c)*NT) * NHW + px;
  float bp = biasp[c];
  #pragma unroll
  for (int n = 0; n < NT; n++) {
    float s = Yr[0] + ((n & 1) ? -Yr[8] : Yr[8]);
    #pragma unroll
    for (int k = 1; k < 8; k++) {
      int j = (k * n) & 15;
      s = fmaf(2.0f * Yr[k], COS16[j], s);
      s = fmaf(-2.0f * Yi[k], SIN16[j], s);
    }
    ob[n * NHW] = xb[n * NHW] + 0.25f * s + bp;
  }
}

extern "C" void kernel_launch(void* const* d_in, const int* in_sizes, int n_in,
                              void* d_out, int out_size, void* d_ws, size_t ws_size,
                              hipStream_t stream) {
  const float* x     = (const float*)d_in[0];
  const float* wcor  = (const float*)d_in[1];
  const float* Wg    = (const float*)d_in[2];
  const float* w1r   = (const float*)d_in[3];
  const float* w1i   = (const float*)d_in[4];
  const float* Wlr   = (const float*)d_in[5];
  const float* Wli   = (const float*)d_in[6];
  const float* gr    = (const float*)d_in[7];
  const float* br    = (const float*)d_in[8];
  const float* gi    = (const float*)d_in[9];
  const float* bi    = (const float*)d_in[10];
  const float* alpha = (const float*)d_in[11];
  const float* biasp = (const float*)d_in[12];
  float* out = (float*)d_out;

  float* ws  = (float*)d_ws;
  float* wo  = ws;                                  // 4*9*16*3136
  float* x2  = wo  + (size_t)NB*9*NT*NHW;           // 4*128*16*3136
  float* xtr = x2  + (size_t)NB*NC*NT*NHW;          // 4*128*9*3136
  float* xti = xtr + (size_t)NB*NC*NF*NHW;
  float* itm = xti + (size_t)NB*NC*NF*NHW;          // 4*144*3136
  float* yr  = itm + (size_t)NB*NO*NHW;
  float* yi  = yr  + (size_t)NB*NC*NF*NHW;
  float* stats = yi + (size_t)NB*NC*NF*NHW;         // 512 floats

  // Aliases (consumed before their regions are overwritten):
  // xcT (4*3136*2208*2B = 55.4MB) sits in xtr/xti region (written later by k_fft).
  // WgBf (144*2208*2B = 636KB) sits in yr region (written later by k_ywl).
  unsigned short* xcT  = (unsigned short*)xtr;
  unsigned short* WgBf = (unsigned short*)yr;

  hipMemsetAsync(stats, 0, 4*NC*sizeof(float), stream);

  dim3 blk(256);
  int pxb = (NHW + 255) / 256;  // 13

  k_wgbf      <<<dim3(NO), blk, 0, stream>>>(Wg, WgBf);
  k_cor       <<<dim3(pxb, NT, NB), blk, 0, stream>>>(x, wcor, wo, x2);
  k_xct       <<<dim3(NHW/32, KSTEPS, NB), blk, 0, stream>>>(x2, wo, xcT);
  k_iterm_mfma<<<dim3(NHW/16, 3, NB), dim3(64), 0, stream>>>(xcT, WgBf, itm);
  k_fft       <<<dim3(pxb, NC, NB), blk, 0, stream>>>(x2, xtr, xti);
  k_ywl       <<<dim3(pxb, 8, NB*NF), blk, 0, stream>>>(xtr, xti, itm, w1r, w1i, Wlr, Wli, yr, yi);
  k_bnstats   <<<dim3(NC, NB), blk, 0, stream>>>(yr, yi, stats);
  k_final     <<<dim3(pxb, NC, NB), blk, 0, stream>>>(yr, yi, stats, gr, br, gi, bi, alpha, biasp, x, out);
}